// Round 1
// baseline (515.607 us; speedup 1.0000x reference)
//
#include <hip/hip_runtime.h>
#include <hip/hip_bf16.h>

typedef unsigned int u32;
typedef unsigned short u16;
typedef __attribute__((ext_vector_type(8))) short bf16x8;
typedef __attribute__((ext_vector_type(4))) float f32x4;
typedef __attribute__((ext_vector_type(4))) u32 u32x4;

__device__ __forceinline__ u16 f2b(float f) {
  u32 x = __builtin_bit_cast(u32, f);
  x = (x + 0x7FFFu + ((x >> 16) & 1u)) >> 16;  // RNE
  return (u16)x;
}
__device__ __forceinline__ float b2f(u16 h) {
  return __builtin_bit_cast(float, ((u32)h) << 16);
}

// ---------- 1. transpose fm (512, 1444) -> fmT (1444, 512) ----------
__global__ void transpose_fm(const float* __restrict__ fm, float* __restrict__ fmT) {
  __shared__ float tile[32][33];
  int pb = blockIdx.x * 32, cb = blockIdx.y * 32;
  int tx = threadIdx.x, ty = threadIdx.y;  // block (32,8)
#pragma unroll
  for (int i = 0; i < 4; ++i) {
    int c = cb + ty + i * 8;
    int p = pb + tx;
    tile[ty + i * 8][tx] = (p < 1444) ? fm[c * 1444 + p] : 0.f;
  }
  __syncthreads();
#pragma unroll
  for (int i = 0; i < 4; ++i) {
    int p = pb + ty + i * 8;
    int c = cb + tx;
    if (p < 1444) fmT[p * 512 + c] = tile[tx][ty + i * 8];
  }
}

// ---------- 2. RoI adaptive max pool -> pooled bf16 [256][25088] ----------
__global__ void roi_pool(const float* __restrict__ fmT,
                         const float* __restrict__ rois,
                         u16* __restrict__ pooled) {
  int n = blockIdx.x;
  int c = blockIdx.y * 256 + threadIdx.x;  // 0..511
  const float* rp = rois + n * 4;
  int y0 = (int)(rp[0] * 0.0625f);
  int x0 = (int)(rp[1] * 0.0625f);
  int y2 = (int)(rp[2] * 0.0625f);
  int x2 = (int)(rp[3] * 0.0625f);
  int h = y2 - y0 + 1;
  int w = x2 - x0 + 1;
  int hsA[7], hlA[7], wsA[7], wlA[7];
#pragma unroll
  for (int i = 0; i < 7; ++i) {
    hsA[i] = (i * h) / 7;
    hlA[i] = ((i + 1) * h + 6) / 7 - hsA[i];
    wsA[i] = (i * w) / 7;
    wlA[i] = ((i + 1) * w + 6) / 7 - wsA[i];
  }
  const float* fp = fmT + c;
  u16* op = pooled + (size_t)n * 25088 + (size_t)c * 49;
  for (int i = 0; i < 7; ++i) {
    int yb = y0 + hsA[i];
    for (int j = 0; j < 7; ++j) {
      int xb = x0 + wsA[j];
      float m = -3.0e38f;
      for (int yy = 0; yy < hlA[i]; ++yy) {
        int y = yb + yy; if (y > 37) y = 37;
        const float* rowp = fp + (size_t)(y * 38) * 512;
        for (int xx = 0; xx < wlA[j]; ++xx) {
          int x = xb + xx; if (x > 37) x = 37;
          m = fmaxf(m, rowp[(size_t)x * 512]);
        }
      }
      op[i * 7 + j] = f2b(m);
    }
  }
}

// ---------- 3. split-K GEMM: C_partial[ks] = A(bf16, Mx K_chunk) * B(f32->bf16) ----------
// M = 256 (full), per-block tile 256x128, BK = 32, 512 threads = 8 waves (4x2 of 64x64).
#define BK 32
__global__ __launch_bounds__(512) void gemm_splitk(
    const u16* __restrict__ A, const float* __restrict__ B,
    float* __restrict__ Cp, int lda, int K_chunk, int nsteps) {
  const int N = 4096;
  int nt = blockIdx.x, ks = blockIdx.y;
  int n0 = nt * 128;
  int k0 = ks * K_chunk;

  // padded rows: 32 k + 8 pad shorts = 80B -> conflict-free b128 frag reads
  __shared__ __align__(16) u16 sA[2][256 * 40];
  __shared__ __align__(16) u16 sB[2][128 * 40];

  int t = threadIdx.x;
  int lane = t & 63;
  int wid = t >> 6;
  int wm = wid >> 1, wn = wid & 1;
  int l4 = lane >> 4, lm = lane & 15;

  int rA = t >> 1, ha = t & 1;  // A staging: row, 16-elem half
  const u16* gA = A + (size_t)rA * lda + k0 + ha * 16;
  int nB = t & 127, kg = t >> 7;  // B staging: col, 8-k group
  const float* gB = B + (size_t)(k0 + kg * 8) * N + n0 + nB;

  f32x4 acc[4][4];
#pragma unroll
  for (int i = 0; i < 4; ++i)
#pragma unroll
    for (int j = 0; j < 4; ++j) acc[i][j] = (f32x4)(0.f);

  u32x4 ra0, ra1;
  float rb[8];

  // prologue: stage step 0 into buf 0
  ra0 = *(const u32x4*)(gA);
  ra1 = *(const u32x4*)(gA + 8);
#pragma unroll
  for (int i = 0; i < 8; ++i) rb[i] = gB[(size_t)i * N];
  {
    *(u32x4*)&sA[0][rA * 40 + ha * 16] = ra0;
    *(u32x4*)&sA[0][rA * 40 + ha * 16 + 8] = ra1;
    u32x4 bw;
    bw[0] = (u32)f2b(rb[0]) | ((u32)f2b(rb[1]) << 16);
    bw[1] = (u32)f2b(rb[2]) | ((u32)f2b(rb[3]) << 16);
    bw[2] = (u32)f2b(rb[4]) | ((u32)f2b(rb[5]) << 16);
    bw[3] = (u32)f2b(rb[6]) | ((u32)f2b(rb[7]) << 16);
    *(u32x4*)&sB[0][nB * 40 + kg * 8] = bw;
  }
  __syncthreads();

  int buf = 0;
  for (int s = 0; s < nsteps; ++s) {
    bool more = (s + 1 < nsteps);
    if (more) {  // issue next-step global loads early (latency hides under MFMA)
      const u16* pa = gA + (size_t)(s + 1) * BK;
      ra0 = *(const u32x4*)(pa);
      ra1 = *(const u32x4*)(pa + 8);
      const float* pb = gB + (size_t)(s + 1) * BK * N;
#pragma unroll
      for (int i = 0; i < 8; ++i) rb[i] = pb[(size_t)i * N];
    }
    // compute current buffer
    const u16* pa0 = &sA[buf][(wm * 64 + lm) * 40 + l4 * 8];
    const u16* pb0 = &sB[buf][(wn * 64 + lm) * 40 + l4 * 8];
    bf16x8 af[4], bfv[4];
#pragma unroll
    for (int m = 0; m < 4; ++m) af[m] = *(const bf16x8*)(pa0 + m * 16 * 40);
#pragma unroll
    for (int n = 0; n < 4; ++n) bfv[n] = *(const bf16x8*)(pb0 + n * 16 * 40);
#pragma unroll
    for (int m = 0; m < 4; ++m)
#pragma unroll
      for (int n = 0; n < 4; ++n)
        acc[m][n] = __builtin_amdgcn_mfma_f32_16x16x32_bf16(af[m], bfv[n], acc[m][n], 0, 0, 0);
    if (more) {  // write-late into the other buffer (safe: nobody reads it this step)
      int nb2 = buf ^ 1;
      *(u32x4*)&sA[nb2][rA * 40 + ha * 16] = ra0;
      *(u32x4*)&sA[nb2][rA * 40 + ha * 16 + 8] = ra1;
      u32x4 bw;
      bw[0] = (u32)f2b(rb[0]) | ((u32)f2b(rb[1]) << 16);
      bw[1] = (u32)f2b(rb[2]) | ((u32)f2b(rb[3]) << 16);
      bw[2] = (u32)f2b(rb[4]) | ((u32)f2b(rb[5]) << 16);
      bw[3] = (u32)f2b(rb[6]) | ((u32)f2b(rb[7]) << 16);
      *(u32x4*)&sB[nb2][nB * 40 + kg * 8] = bw;
    }
    __syncthreads();
    buf ^= 1;
  }

  // epilogue: partial C [ks][256][4096]
#pragma unroll
  for (int m = 0; m < 4; ++m) {
#pragma unroll
    for (int n = 0; n < 4; ++n) {
      int grow = wm * 64 + m * 16 + l4 * 4;
      int gcol = n0 + wn * 64 + n * 16 + lm;
      float* cp = Cp + ((size_t)(ks * 256 + grow)) * 4096 + gcol;
#pragma unroll
      for (int r = 0; r < 4; ++r) cp[(size_t)r * 4096] = acc[m][n][r];
    }
  }
}

// ---------- 4. reduce split-K partials + bias + relu -> bf16 ----------
__global__ void reduce_bias_relu(const float* __restrict__ Cp,
                                 const float* __restrict__ bias,
                                 u16* __restrict__ outbf) {
  int idx = blockIdx.x * 256 + threadIdx.x;  // 256*4096 total
  float s = bias[idx & 4095];
#pragma unroll
  for (int k = 0; k < 8; ++k) s += Cp[(size_t)k * 1048576 + idx];
  s = fmaxf(s, 0.f);
  outbf[idx] = f2b(s);
}

// ---------- 5. heads: locs = fc7@Wloc+bloc ; scores = fc7@Wsc+bsc ----------
__global__ __launch_bounds__(512) void heads_kernel(
    const u16* __restrict__ fc7,
    const float* __restrict__ Wloc, const float* __restrict__ bloc,
    const float* __restrict__ Wsc, const float* __restrict__ bsc,
    float* __restrict__ out) {
  int t = threadIdx.x;
  int c = t & 127, sl = t >> 7;  // 105 active cols, 4 k-slices
  int r0 = blockIdx.x * 4;       // 4 rois per block
  const u16* f0 = fc7 + (size_t)r0 * 4096;
  float acc0 = 0.f, acc1 = 0.f, acc2 = 0.f, acc3 = 0.f;
  if (c < 105) {
    int kb = sl * 1024;
#pragma unroll 4
    for (int k = kb; k < kb + 1024; ++k) {
      float wv = (c < 84) ? Wloc[(size_t)k * 84 + c] : Wsc[(size_t)k * 21 + (c - 84)];
      acc0 += b2f(f0[k]) * wv;
      acc1 += b2f(f0[4096 + k]) * wv;
      acc2 += b2f(f0[8192 + k]) * wv;
      acc3 += b2f(f0[12288 + k]) * wv;
    }
  }
  __shared__ float red[4][4][128];
  red[sl][0][c] = acc0;
  red[sl][1][c] = acc1;
  red[sl][2][c] = acc2;
  red[sl][3][c] = acc3;
  __syncthreads();
  if (sl == 0 && c < 105) {
#pragma unroll
    for (int q = 0; q < 4; ++q) {
      float s = red[0][q][c] + red[1][q][c] + red[2][q][c] + red[3][q][c];
      int r = r0 + q;
      if (c < 84) out[(size_t)r * 84 + c] = s + bloc[c];
      else out[21504 + (size_t)r * 21 + (c - 84)] = s + bsc[c - 84];
    }
  }
}

extern "C" void kernel_launch(void* const* d_in, const int* in_sizes, int n_in,
                              void* d_out, int out_size, void* d_ws, size_t ws_size,
                              hipStream_t stream) {
  const float* fm   = (const float*)d_in[0];
  const float* rois = (const float*)d_in[1];
  const float* W1   = (const float*)d_in[2];
  const float* b1   = (const float*)d_in[3];
  const float* W2   = (const float*)d_in[4];
  const float* b2   = (const float*)d_in[5];
  const float* Wloc = (const float*)d_in[6];
  const float* bloc = (const float*)d_in[7];
  const float* Wsc  = (const float*)d_in[8];
  const float* bsc  = (const float*)d_in[9];
  float* out = (float*)d_out;

  char* ws = (char*)d_ws;
  float* fmT   = (float*)(ws);               // 1444*512*4   = 2,957,312 B
  u16*  pooled = (u16*)(ws + 2957312);       // 256*25088*2  = 12,845,056 B
  u16*  fc6    = (u16*)(ws + 15802368);      // 256*4096*2   = 2,097,152 B
  u16*  fc7    = (u16*)(ws + 17899520);      // 256*4096*2   = 2,097,152 B
  float* Cp    = (float*)(ws + 19996672);    // 8*256*4096*4 = 33,554,432 B (reused)

  transpose_fm<<<dim3(46, 16), dim3(32, 8), 0, stream>>>(fm, fmT);
  roi_pool<<<dim3(256, 2), 256, 0, stream>>>(fmT, rois, pooled);
  gemm_splitk<<<dim3(32, 8), 512, 0, stream>>>(pooled, W1, Cp, 25088, 3136, 98);
  reduce_bias_relu<<<4096, 256, 0, stream>>>(Cp, b1, fc6);
  gemm_splitk<<<dim3(32, 8), 512, 0, stream>>>(fc6, W2, Cp, 4096, 512, 16);
  reduce_bias_relu<<<4096, 256, 0, stream>>>(Cp, b2, fc7);
  heads_kernel<<<64, 512, 0, stream>>>(fc7, Wloc, bloc, Wsc, bsc, out);
}